// Round 8
// baseline (147.599 us; speedup 1.0000x reference)
//
#include <hip/hip_runtime.h>
#include <hip/hip_bf16.h>
#include <cmath>

// GRU cell fused, round 8: round-7 shell, but W (B-operand) fragments are
// loaded DIRECTLY global->VGPR from the pre-swizzled ws image (L2-resident:
// block order i=bid&63, j=bid>>6 keeps ~64 co-resident blocks on one j, so
// the live W slice is 768KB << 4MB/XCD L2). Only A flows through LDS
// (2 x 16KB dbuf, 4 DMA chunks/wave/step). This removes 12/20 of the LDS
// reads and 60% of the DMA-LDS writes per step, decoupling the LDS pipe
// from the MFMA pipe.
// ws layout (ushort elems) — identical to rounds 1/7:
//   wsIn  @ 0        : [64 mtile][32 kstep][128x32 swz]
//   wsHx  @ 8388608
//   wsWih @ 16777216 : [32 ntile][32 kstep][64x32 swz]
//   wsWhh @ 18874368
//   wsWc  @ 20971520
//   wsWhc @ 22020096

typedef __attribute__((ext_vector_type(8))) short bf16x8;
typedef __attribute__((ext_vector_type(4))) float f32x4;
typedef unsigned int u32;

typedef const __attribute__((address_space(1))) u32 gu32;
typedef __attribute__((address_space(3))) u32 su32;

__device__ __forceinline__ unsigned short f2bf(float f) {
  union { float f; u32 u; } v; v.f = f;
  u32 u = v.u;
  u += 0x7FFFu + ((u >> 16) & 1u);   // RTNE
  return (unsigned short)(u >> 16);
}
__device__ __forceinline__ void gload16(void* ldsp, const void* gp) {
  __builtin_amdgcn_global_load_lds((gu32*)gp, (su32*)ldsp, 16, 0, 0);
}
__device__ __forceinline__ float sigmf(float x) { return 1.0f / (1.0f + __expf(-x)); }

// ---------------- merged prepass: fp32 -> bf16 swizzled tiles (proven) ----------------
__global__ __launch_bounds__(256) void cvt_all(
    const float* __restrict__ In, const float* __restrict__ Hx,
    const float* __restrict__ Wih, const float* __restrict__ Whh,
    const float* __restrict__ Wc,  const float* __restrict__ Whc,
    unsigned short* __restrict__ wsIn, unsigned short* __restrict__ wsHx,
    unsigned short* __restrict__ wsWih, unsigned short* __restrict__ wsWhh,
    unsigned short* __restrict__ wsWc,  unsigned short* __restrict__ wsWhc)
{
  int bid = blockIdx.x;
  if (bid < 8192) {
    int gid = bid * 256 + threadIdx.x;
    const float* src; unsigned short* dst; int idx;
    if (gid < (1 << 20)) { src = In; dst = wsIn; idx = gid; }
    else                 { src = Hx; dst = wsHx; idx = gid - (1 << 20); }
    int m = idx >> 7, t = idx & 127;
    const float4* s = (const float4*)(src + (size_t)m * 1024 + t * 8);
    float4 a = s[0], b = s[1];
    int row = m & 127;
    size_t tile = (size_t)(m >> 7) * 32 + (t >> 2);
    int sw = (t & 3) ^ ((row >> 1) & 3);
    bf16x8 v;
    v[0] = (short)f2bf(a.x); v[1] = (short)f2bf(a.y); v[2] = (short)f2bf(a.z); v[3] = (short)f2bf(a.w);
    v[4] = (short)f2bf(b.x); v[5] = (short)f2bf(b.y); v[6] = (short)f2bf(b.z); v[7] = (short)f2bf(b.w);
    *(bf16x8*)(dst + tile * 4096 + row * 32 + sw * 8) = v;
  } else {
    int wb = bid - 8192;
    const float* W; unsigned short* dst; int NW; int local;
    if (wb < 1024)      { W = Wih; dst = wsWih; NW = 2048; local = wb; }
    else if (wb < 2048) { W = Whh; dst = wsWhh; NW = 2048; local = wb - 1024; }
    else if (wb < 2560) { W = Wc;  dst = wsWc;  NW = 1024; local = wb - 2048; }
    else                { W = Whc; dst = wsWhc; NW = 1024; local = wb - 2560; }
    int nb = local >> 5, kb = local & 31;
    int n  = nb * 64 + (threadIdx.x & 63);
    int k0 = kb * 32 + (threadIdx.x >> 6) * 8;
    bf16x8 v;
    #pragma unroll
    for (int b = 0; b < 8; ++b) v[b] = (short)f2bf(W[(size_t)(k0 + b) * NW + n]);
    int row = n & 63;
    size_t tile = (size_t)(n >> 6) * 32 + (k0 >> 5);
    int sw = ((k0 >> 3) & 3) ^ ((row >> 1) & 3);
    *(bf16x8*)(dst + tile * 2048 + row * 32 + sw * 8) = v;
  }
}

// ---------------- fused GEMM + GRU epilogue, W-from-L2 ----------------
// block: 256 thr = 4 waves (2x2), tile BM=128 x BN=64, BK=32.
// LDS: 2 x 8192 ushorts (A only: sIn[0,4096) sHx[4096,8192) per buffer).
__global__ __launch_bounds__(256, 2) void gru_gemm(
    const unsigned short* __restrict__ ws,
    const float* __restrict__ Hx,
    const float* __restrict__ bih, const float* __restrict__ bhh,
    const float* __restrict__ bc, const float* __restrict__ bhc,
    float* __restrict__ out)
{
  __shared__ unsigned short lds[16384];   // 32 KB = 2 x 16 KB
  const int tid  = threadIdx.x;
  const int lane = tid & 63;
  const int wave = tid >> 6;
  const int wm = wave >> 1, wn = wave & 1;
  const int bid = blockIdx.x;
  const int i = bid & 63;      // m-block (128 rows) — fastest: co-resident blocks share j
  const int j = bid >> 6;      // n-block (64 cols)
  const int r15 = lane & 15;
  const int q   = lane >> 4;

  // ---- W uniform bases (ushort offsets into ws), per matrix ----
  // order: 0=Wih_z 1=Wih_r 2=Whh_z 3=Whh_r 4=Wc 5=Whc
  u32 wb[6];
  wb[0] = 16777216u + (u32)j * 65536u;
  wb[1] = 16777216u + (u32)(j + 16) * 65536u;
  wb[2] = 18874368u + (u32)j * 65536u;
  wb[3] = 18874368u + (u32)(j + 16) * 65536u;
  wb[4] = 20971520u + (u32)j * 65536u;
  wb[5] = 22020096u + (u32)j * 65536u;
  // per-lane fragment offset within a [64x32 swz] k-step tile; nr=1 adds 512
  const int rw = wn * 32 + r15;
  const u32 vo = (u32)(rw * 32 + ((q ^ ((rw >> 1) & 3)) << 3));

  // ---- A staging plan: 16 chunks of 1KB; this wave's 4 ----
  const unsigned short* srcA[4];
  #pragma unroll
  for (int c0 = 0; c0 < 4; ++c0) {
    int c = wave * 4 + c0;
    srcA[c0] = (c < 8 ? ws + (size_t)i * 131072 + c * 512
                      : ws + 8388608 + (size_t)i * 131072 + (c - 8) * 512) + lane * 8;
  }
  const int dstA = wave * 4 * 512;

  // ---- A LDS read offsets ----
  int aOff[4];
  #pragma unroll
  for (int mr = 0; mr < 4; ++mr) {
    int row = wm * 64 + mr * 16 + r15;
    aOff[mr] = row * 32 + ((q ^ ((row >> 1) & 3)) << 3);
  }

  f32x4 accZ[4][2], accR[4][2], accC[4][2], accH[4][2];
  #pragma unroll
  for (int a = 0; a < 4; ++a)
    #pragma unroll
    for (int b = 0; b < 2; ++b) {
      accZ[a][b] = (f32x4)(0.0f); accR[a][b] = (f32x4)(0.0f);
      accC[a][b] = (f32x4)(0.0f); accH[a][b] = (f32x4)(0.0f);
    }

  auto stage = [&](int bufBase, int s) {
    #pragma unroll
    for (int c0 = 0; c0 < 4; ++c0)
      gload16((void*)&lds[bufBase + dstA + c0 * 512],
              (const void*)(srcA[c0] + (size_t)s * 4096));
  };

  auto step = [&](int B, int t, int OB, int sNext, bool doStage) {
    // 1) W fragments for step t: direct global->VGPR (L2-hit)
    bf16x8 wf[6][2];
    #pragma unroll
    for (int m = 0; m < 6; ++m) {
      wf[m][0] = *(const bf16x8*)(ws + wb[m] + (u32)t * 2048u + vo);
      wf[m][1] = *(const bf16x8*)(ws + wb[m] + (u32)t * 2048u + vo + 512u);
    }
    // 2) stage A(t+1) into the other buffer (DMA, drains at the barrier)
    if (doStage) stage(OB, sNext);
    // 3) A fragments from LDS
    bf16x8 aIn[4], aHx[4];
    #pragma unroll
    for (int mr = 0; mr < 4; ++mr) {
      aIn[mr] = *(const bf16x8*)&lds[B + aOff[mr]];
      aHx[mr] = *(const bf16x8*)&lds[B + 4096 + aOff[mr]];
    }
    // 4) 48 MFMA (compiler inserts counted vmcnt/lgkmcnt before first uses)
    #pragma unroll
    for (int mr = 0; mr < 4; ++mr)
      #pragma unroll
      for (int nr = 0; nr < 2; ++nr) {
        accZ[mr][nr] = __builtin_amdgcn_mfma_f32_16x16x32_bf16(aIn[mr], wf[0][nr], accZ[mr][nr], 0, 0, 0);
        accZ[mr][nr] = __builtin_amdgcn_mfma_f32_16x16x32_bf16(aHx[mr], wf[2][nr], accZ[mr][nr], 0, 0, 0);
        accR[mr][nr] = __builtin_amdgcn_mfma_f32_16x16x32_bf16(aIn[mr], wf[1][nr], accR[mr][nr], 0, 0, 0);
        accR[mr][nr] = __builtin_amdgcn_mfma_f32_16x16x32_bf16(aHx[mr], wf[3][nr], accR[mr][nr], 0, 0, 0);
        accC[mr][nr] = __builtin_amdgcn_mfma_f32_16x16x32_bf16(aIn[mr], wf[4][nr], accC[mr][nr], 0, 0, 0);
        accH[mr][nr] = __builtin_amdgcn_mfma_f32_16x16x32_bf16(aHx[mr], wf[5][nr], accH[mr][nr], 0, 0, 0);
      }
    __syncthreads();   // A(t+1) DMA landed; all reads of buf B complete
  };

  // prologue: stage step 0 into buf0
  stage(0, 0);
  __syncthreads();

  #pragma unroll 1
  for (int it = 0; it < 16; ++it) {
    const int s = it * 2;
    step(0,    s,     8192, s + 1, true);
    step(8192, s + 1, 0,    s + 2, it < 15);
  }

  // epilogue: D layout col = lane&15 (n), row = q*4+v (m)
  const int n0 = j * 64 + wn * 32;
  const int m0 = i * 128 + wm * 64;
  #pragma unroll
  for (int nr = 0; nr < 2; ++nr) {
    int n = n0 + nr * 16 + r15;
    float bz  = bih[n] + bhh[n];
    float br  = bih[1024 + n] + bhh[1024 + n];
    float bcv = bc[n], bhcv = bhc[n];
    #pragma unroll
    for (int mr = 0; mr < 4; ++mr) {
      #pragma unroll
      for (int v = 0; v < 4; ++v) {
        int m = m0 + mr * 16 + q * 4 + v;
        float z  = sigmf(accZ[mr][nr][v] + bz);
        float rr = sigmf(accR[mr][nr][v] + br);
        float cd = tanhf(accC[mr][nr][v] + bcv + rr * (accH[mr][nr][v] + bhcv));
        float h  = Hx[(size_t)m * 1024 + n];
        out[(size_t)m * 1024 + n] = (1.0f - z) * h + z * cd;
      }
    }
  }
}

// ---------------- last-resort fp32 fallback ----------------
__global__ __launch_bounds__(256) void gru_fallback(
    const float* __restrict__ In, const float* __restrict__ Hx,
    const float* __restrict__ Wih, const float* __restrict__ bih,
    const float* __restrict__ Whh, const float* __restrict__ bhh,
    const float* __restrict__ Wc, const float* __restrict__ bc,
    const float* __restrict__ Whc, const float* __restrict__ bhc,
    float* __restrict__ out)
{
  __shared__ float sIn[64][17], sHx[64][17];
  __shared__ float sW[6][16][68];
  const int tid = threadIdx.x;
  const int j = blockIdx.x & 15, i = blockIdx.x >> 4;
  const int tx = tid & 15, ty = tid >> 4;
  float accZ[4][4] = {}, accR[4][4] = {}, accC[4][4] = {}, accH[4][4] = {};
  const int ms = tid >> 2, kq = (tid & 3) * 4;
  const int wk = tid >> 4, wn4 = (tid & 15) * 4;
  for (int k0 = 0; k0 < 1024; k0 += 16) {
    __syncthreads();
    {
      float4 a = *(const float4*)&In[(size_t)(i * 64 + ms) * 1024 + k0 + kq];
      sIn[ms][kq] = a.x; sIn[ms][kq + 1] = a.y; sIn[ms][kq + 2] = a.z; sIn[ms][kq + 3] = a.w;
      float4 b = *(const float4*)&Hx[(size_t)(i * 64 + ms) * 1024 + k0 + kq];
      sHx[ms][kq] = b.x; sHx[ms][kq + 1] = b.y; sHx[ms][kq + 2] = b.z; sHx[ms][kq + 3] = b.w;
    }
    {
      float4 w0 = *(const float4*)&Wih[(size_t)(k0 + wk) * 2048 + j * 64 + wn4];
      float4 w1 = *(const float4*)&Wih[(size_t)(k0 + wk) * 2048 + 1024 + j * 64 + wn4];
      float4 w2 = *(const float4*)&Whh[(size_t)(k0 + wk) * 2048 + j * 64 + wn4];
      float4 w3 = *(const float4*)&Whh[(size_t)(k0 + wk) * 2048 + 1024 + j * 64 + wn4];
      float4 w4 = *(const float4*)&Wc[(size_t)(k0 + wk) * 1024 + j * 64 + wn4];
      float4 w5 = *(const float4*)&Whc[(size_t)(k0 + wk) * 1024 + j * 64 + wn4];
      sW[0][wk][wn4] = w0.x; sW[0][wk][wn4+1] = w0.y; sW[0][wk][wn4+2] = w0.z; sW[0][wk][wn4+3] = w0.w;
      sW[1][wk][wn4] = w1.x; sW[1][wk][wn4+1] = w1.y; sW[1][wk][wn4+2] = w1.z; sW[1][wk][wn4+3] = w1.w;
      sW[2][wk][wn4] = w2.x; sW[2][wk][wn4+1] = w2.y; sW[2][wk][wn4+2] = w2.z; sW[2][wk][wn4+3] = w2.w;
      sW[3][wk][wn4] = w3.x; sW[3][wk][wn4+1] = w3.y; sW[3][wk][wn4+2] = w3.z; sW[3][wk][wn4+3] = w3.w;
      sW[4][wk][wn4] = w4.x; sW[4][wk][wn4+1] = w4.y; sW[4][wk][wn4+2] = w4.z; sW[4][wk][wn4+3] = w4.w;
      sW[5][wk][wn4] = w5.x; sW[5][wk][wn4+1] = w5.y; sW[5][wk][wn4+2] = w5.z; sW[5][wk][wn4+3] = w5.w;
    }
    __syncthreads();
    for (int kk = 0; kk < 16; ++kk) {
      float aI[4], aH[4];
      #pragma unroll
      for (int im = 0; im < 4; ++im) { aI[im] = sIn[ty * 4 + im][kk]; aH[im] = sHx[ty * 4 + im][kk]; }
      #pragma unroll
      for (int jn = 0; jn < 4; ++jn) {
        float w0 = sW[0][kk][tx * 4 + jn], w1 = sW[1][kk][tx * 4 + jn], w2 = sW[2][kk][tx * 4 + jn];
        float w3 = sW[3][kk][tx * 4 + jn], w4 = sW[4][kk][tx * 4 + jn], w5 = sW[5][kk][tx * 4 + jn];
        #pragma unroll
        for (int im = 0; im < 4; ++im) {
          accZ[im][jn] += aI[im] * w0 + aH[im] * w2;
          accR[im][jn] += aI[im] * w1 + aH[im] * w3;
          accC[im][jn] += aI[im] * w4;
          accH[im][jn] += aH[im] * w5;
        }
      }
    }
  }
  #pragma unroll
  for (int jn = 0; jn < 4; ++jn) {
    int n = j * 64 + tx * 4 + jn;
    float bz  = bih[n] + bhh[n];
    float br  = bih[1024 + n] + bhh[1024 + n];
    float bcv = bc[n], bhcv = bhc[n];
    #pragma unroll
    for (int im = 0; im < 4; ++im) {
      int m = i * 64 + ty * 4 + im;
      float z  = sigmf(accZ[im][jn] + bz);
      float rr = sigmf(accR[im][jn] + br);
      float cd = tanhf(accC[im][jn] + bcv + rr * (accH[im][jn] + bhcv));
      float h  = Hx[(size_t)m * 1024 + n];
      out[(size_t)m * 1024 + n] = (1.0f - z) * h + z * cd;
    }
  }
}

extern "C" void kernel_launch(void* const* d_in, const int* in_sizes, int n_in,
                              void* d_out, int out_size, void* d_ws, size_t ws_size,
                              hipStream_t stream) {
  const float* In  = (const float*)d_in[0];
  const float* Hx  = (const float*)d_in[1];
  const float* Wih = (const float*)d_in[2];
  const float* bih = (const float*)d_in[3];
  const float* Whh = (const float*)d_in[4];
  const float* bhh = (const float*)d_in[5];
  const float* Wc  = (const float*)d_in[6];
  const float* bc  = (const float*)d_in[7];
  const float* Whc = (const float*)d_in[8];
  const float* bhc = (const float*)d_in[9];
  float* out = (float*)d_out;

  const size_t WS_NEED = 46137344ull;
  if (ws_size >= WS_NEED) {
    unsigned short* ws    = (unsigned short*)d_ws;
    unsigned short* wsIn  = ws;
    unsigned short* wsHx  = ws + 8388608;
    unsigned short* wsWih = ws + 16777216;
    unsigned short* wsWhh = ws + 18874368;
    unsigned short* wsWc  = ws + 20971520;
    unsigned short* wsWhc = ws + 22020096;
    cvt_all<<<11264, 256, 0, stream>>>(In, Hx, Wih, Whh, Wc, Whc,
                                       wsIn, wsHx, wsWih, wsWhh, wsWc, wsWhc);
    gru_gemm<<<1024, 256, 0, stream>>>(ws, Hx, bih, bhh, bc, bhc, out);
  } else {
    gru_fallback<<<2048, 256, 0, stream>>>(In, Hx, Wih, bih, Whh, bhh, Wc, bc, Whc, bhc, out);
  }
}

// Round 9
// 142.094 us; speedup vs baseline: 1.0387x; 1.0387x over previous
//
#include <hip/hip_runtime.h>
#include <hip/hip_bf16.h>
#include <cmath>

// GRU cell fused, round 9: W direct global->VGPR (L2-resident) with ONE-STEP
// REGISTER PREFETCH: each W fragment is reloaded for step t+1 immediately
// after its last MFMA use in step t; the end-of-step __syncthreads() vmcnt
// drain guarantees arrival (no exposed latency — fixes round 8's flaw).
// A stays in LDS (2 x 16KB dbuf, DMA staged one step ahead).
// LDS pipe now carries only A (reads+DMA ~1300cy/paired-step) and MFMA
// (~1536cy/SIMD) becomes the binding pipe; W rides VMEM/L2 in parallel.
// ws layout (ushort elems) — identical to rounds 1/7/8:
//   wsIn  @ 0        : [64 mtile][32 kstep][128x32 swz]
//   wsHx  @ 8388608
//   wsWih @ 16777216 : [32 ntile][32 kstep][64x32 swz]
//   wsWhh @ 18874368
//   wsWc  @ 20971520
//   wsWhc @ 22020096

typedef __attribute__((ext_vector_type(8))) short bf16x8;
typedef __attribute__((ext_vector_type(4))) float f32x4;
typedef unsigned int u32;

typedef const __attribute__((address_space(1))) u32 gu32;
typedef __attribute__((address_space(3))) u32 su32;

__device__ __forceinline__ unsigned short f2bf(float f) {
  union { float f; u32 u; } v; v.f = f;
  u32 u = v.u;
  u += 0x7FFFu + ((u >> 16) & 1u);   // RTNE
  return (unsigned short)(u >> 16);
}
__device__ __forceinline__ void gload16(void* ldsp, const void* gp) {
  __builtin_amdgcn_global_load_lds((gu32*)gp, (su32*)ldsp, 16, 0, 0);
}
__device__ __forceinline__ float sigmf(float x) { return 1.0f / (1.0f + __expf(-x)); }

// ---------------- merged prepass: fp32 -> bf16 swizzled tiles (proven) ----------------
__global__ __launch_bounds__(256) void cvt_all(
    const float* __restrict__ In, const float* __restrict__ Hx,
    const float* __restrict__ Wih, const float* __restrict__ Whh,
    const float* __restrict__ Wc,  const float* __restrict__ Whc,
    unsigned short* __restrict__ wsIn, unsigned short* __restrict__ wsHx,
    unsigned short* __restrict__ wsWih, unsigned short* __restrict__ wsWhh,
    unsigned short* __restrict__ wsWc,  unsigned short* __restrict__ wsWhc)
{
  int bid = blockIdx.x;
  if (bid < 8192) {
    int gid = bid * 256 + threadIdx.x;
    const float* src; unsigned short* dst; int idx;
    if (gid < (1 << 20)) { src = In; dst = wsIn; idx = gid; }
    else                 { src = Hx; dst = wsHx; idx = gid - (1 << 20); }
    int m = idx >> 7, t = idx & 127;
    const float4* s = (const float4*)(src + (size_t)m * 1024 + t * 8);
    float4 a = s[0], b = s[1];
    int row = m & 127;
    size_t tile = (size_t)(m >> 7) * 32 + (t >> 2);
    int sw = (t & 3) ^ ((row >> 1) & 3);
    bf16x8 v;
    v[0] = (short)f2bf(a.x); v[1] = (short)f2bf(a.y); v[2] = (short)f2bf(a.z); v[3] = (short)f2bf(a.w);
    v[4] = (short)f2bf(b.x); v[5] = (short)f2bf(b.y); v[6] = (short)f2bf(b.z); v[7] = (short)f2bf(b.w);
    *(bf16x8*)(dst + tile * 4096 + row * 32 + sw * 8) = v;
  } else {
    int wb = bid - 8192;
    const float* W; unsigned short* dst; int NW; int local;
    if (wb < 1024)      { W = Wih; dst = wsWih; NW = 2048; local = wb; }
    else if (wb < 2048) { W = Whh; dst = wsWhh; NW = 2048; local = wb - 1024; }
    else if (wb < 2560) { W = Wc;  dst = wsWc;  NW = 1024; local = wb - 2048; }
    else                { W = Whc; dst = wsWhc; NW = 1024; local = wb - 2560; }
    int nb = local >> 5, kb = local & 31;
    int n  = nb * 64 + (threadIdx.x & 63);
    int k0 = kb * 32 + (threadIdx.x >> 6) * 8;
    bf16x8 v;
    #pragma unroll
    for (int b = 0; b < 8; ++b) v[b] = (short)f2bf(W[(size_t)(k0 + b) * NW + n]);
    int row = n & 63;
    size_t tile = (size_t)(n >> 6) * 32 + (k0 >> 5);
    int sw = ((k0 >> 3) & 3) ^ ((row >> 1) & 3);
    *(bf16x8*)(dst + tile * 2048 + row * 32 + sw * 8) = v;
  }
}

// ---------------- fused GEMM + GRU epilogue, W-in-reg pipelined ----------------
// block: 256 thr = 4 waves (2x2), tile BM=128 x BN=64, BK=32.
// LDS: 2 x 8192 ushorts (A only). Block order: i=bid&63 fastest (shared j in L2).
__global__ __launch_bounds__(256, 2) void gru_gemm(
    const unsigned short* __restrict__ ws,
    const float* __restrict__ Hx,
    const float* __restrict__ bih, const float* __restrict__ bhh,
    const float* __restrict__ bc, const float* __restrict__ bhc,
    float* __restrict__ out)
{
  __shared__ unsigned short lds[16384];   // 32 KB = 2 x 16 KB
  const int tid  = threadIdx.x;
  const int lane = tid & 63;
  const int wave = tid >> 6;
  const int wm = wave >> 1, wn = wave & 1;
  const int bid = blockIdx.x;
  const int i = bid & 63;      // m-block (128 rows)
  const int j = bid >> 6;      // n-block (64 cols)
  const int r15 = lane & 15;
  const int q   = lane >> 4;

  // ---- W per-lane fragment pointers (ushort offsets into ws) ----
  // order: 0=Wih_z 1=Wih_r 2=Whh_z 3=Whh_r 4=Wc 5=Whc
  const int rw = wn * 32 + r15;
  const u32 vo = (u32)(rw * 32 + ((q ^ ((rw >> 1) & 3)) << 3));
  const unsigned short* Wp0 = ws + 16777216u + (u32)j * 65536u + vo;
  const unsigned short* Wp1 = ws + 16777216u + (u32)(j + 16) * 65536u + vo;
  const unsigned short* Wp2 = ws + 18874368u + (u32)j * 65536u + vo;
  const unsigned short* Wp3 = ws + 18874368u + (u32)(j + 16) * 65536u + vo;
  const unsigned short* Wp4 = ws + 20971520u + (u32)j * 65536u + vo;
  const unsigned short* Wp5 = ws + 22020096u + (u32)j * 65536u + vo;

  // ---- A staging plan: 16 chunks of 1KB; this wave's 4 ----
  const unsigned short* srcA[4];
  #pragma unroll
  for (int c0 = 0; c0 < 4; ++c0) {
    int c = wave * 4 + c0;
    srcA[c0] = (c < 8 ? ws + (size_t)i * 131072 + c * 512
                      : ws + 8388608 + (size_t)i * 131072 + (c - 8) * 512) + lane * 8;
  }
  const int dstA = wave * 4 * 512;

  int aOff[4];
  #pragma unroll
  for (int mr = 0; mr < 4; ++mr) {
    int row = wm * 64 + mr * 16 + r15;
    aOff[mr] = row * 32 + ((q ^ ((row >> 1) & 3)) << 3);
  }

  f32x4 accZ[4][2], accR[4][2], accC[4][2], accH[4][2];
  #pragma unroll
  for (int a = 0; a < 4; ++a)
    #pragma unroll
    for (int b = 0; b < 2; ++b) {
      accZ[a][b] = (f32x4)(0.0f); accR[a][b] = (f32x4)(0.0f);
      accC[a][b] = (f32x4)(0.0f); accH[a][b] = (f32x4)(0.0f);
    }

  auto stage = [&](int bufBase, int s) {
    #pragma unroll
    for (int c0 = 0; c0 < 4; ++c0)
      gload16((void*)&lds[bufBase + dstA + c0 * 512],
              (const void*)(srcA[c0] + (size_t)s * 4096));
  };

  // persistent W fragment registers (loaded for step t during step t-1)
  bf16x8 w0a, w0b, w1a, w1b, w2a, w2b, w3a, w3b, w4a, w4b, w5a, w5b;
  #define LOADW(v, P, NR, T) v = *(const bf16x8*)((P) + (u32)(T) * 2048u + (u32)(NR) * 512u)

  #define MFMA_(a,b,c) __builtin_amdgcn_mfma_f32_16x16x32_bf16(a, b, c, 0, 0, 0)

  // One K-step: A from LDS buf B; W(t) already in regs; reload W(t+1=TN)
  // right after each matrix's last use; stage A(SN) into other buf OB.
  #define STEP(B, OB, SN, TN, DOSTAGE) {                                         \
    if (DOSTAGE) stage(OB, SN);                                                  \
    bf16x8 aIn[4], aHx[4];                                                       \
    _Pragma("unroll")                                                            \
    for (int mr = 0; mr < 4; ++mr) {                                             \
      aIn[mr] = *(const bf16x8*)&lds[(B) + aOff[mr]];                            \
      aHx[mr] = *(const bf16x8*)&lds[(B) + 4096 + aOff[mr]];                     \
    }                                                                            \
    _Pragma("unroll")                                                            \
    for (int mr = 0; mr < 4; ++mr) {                                             \
      accZ[mr][0] = MFMA_(aIn[mr], w0a, accZ[mr][0]);                            \
      accZ[mr][1] = MFMA_(aIn[mr], w0b, accZ[mr][1]);                            \
      accZ[mr][0] = MFMA_(aHx[mr], w2a, accZ[mr][0]);                            \
      accZ[mr][1] = MFMA_(aHx[mr], w2b, accZ[mr][1]);                            \
    }                                                                            \
    LOADW(w0a, Wp0, 0, TN); LOADW(w0b, Wp0, 1, TN);                              \
    LOADW(w2a, Wp2, 0, TN); LOADW(w2b, Wp2, 1, TN);                              \
    _Pragma("unroll")                                                            \
    for (int mr = 0; mr < 4; ++mr) {                                             \
      accR[mr][0] = MFMA_(aIn[mr], w1a, accR[mr][0]);                            \
      accR[mr][1] = MFMA_(aIn[mr], w1b, accR[mr][1]);                            \
      accR[mr][0] = MFMA_(aHx[mr], w3a, accR[mr][0]);                            \
      accR[mr][1] = MFMA_(aHx[mr], w3b, accR[mr][1]);                            \
    }                                                                            \
    LOADW(w1a, Wp1, 0, TN); LOADW(w1b, Wp1, 1, TN);                              \
    LOADW(w3a, Wp3, 0, TN); LOADW(w3b, Wp3, 1, TN);                              \
    _Pragma("unroll")                                                            \
    for (int mr = 0; mr < 4; ++mr) {                                             \
      accC[mr][0] = MFMA_(aIn[mr], w4a, accC[mr][0]);                            \
      accC[mr][1] = MFMA_(aIn[mr], w4b, accC[mr][1]);                            \
      accH[mr][0] = MFMA_(aHx[mr], w5a, accH[mr][0]);                            \
      accH[mr][1] = MFMA_(aHx[mr], w5b, accH[mr][1]);                            \
    }                                                                            \
    LOADW(w4a, Wp4, 0, TN); LOADW(w4b, Wp4, 1, TN);                              \
    LOADW(w5a, Wp5, 0, TN); LOADW(w5b, Wp5, 1, TN);                              \
    __syncthreads();  /* drains A-DMA(SN) and W(TN) loads */                     \
  }

  // ---------- prologue: A(0) DMA + W(0) regs ----------
  stage(0, 0);
  LOADW(w0a, Wp0, 0, 0); LOADW(w0b, Wp0, 1, 0);
  LOADW(w2a, Wp2, 0, 0); LOADW(w2b, Wp2, 1, 0);
  LOADW(w1a, Wp1, 0, 0); LOADW(w1b, Wp1, 1, 0);
  LOADW(w3a, Wp3, 0, 0); LOADW(w3b, Wp3, 1, 0);
  LOADW(w4a, Wp4, 0, 0); LOADW(w4b, Wp4, 1, 0);
  LOADW(w5a, Wp5, 0, 0); LOADW(w5b, Wp5, 1, 0);
  __syncthreads();

  #pragma unroll 1
  for (int it = 0; it < 16; ++it) {
    const int s = it * 2;
    const int t1 = s + 1;                       // always <= 31
    const int t2 = s + 2 <= 31 ? s + 2 : 31;    // clamp (redundant reload at tail)
    STEP(0,    8192, t1, t1, true)
    STEP(8192, 0,    t2, t2, it < 15)
  }
  #undef STEP
  #undef LOADW
  #undef MFMA_

  // ---------- epilogue: D layout col = lane&15 (n), row = q*4+v (m) ----------
  const int n0 = j * 64 + wn * 32;
  const int m0 = i * 128 + wm * 64;
  #pragma unroll
  for (int nr = 0; nr < 2; ++nr) {
    int n = n0 + nr * 16 + r15;
    float bz  = bih[n] + bhh[n];
    float br  = bih[1024 + n] + bhh[1024 + n];
    float bcv = bc[n], bhcv = bhc[n];
    #pragma unroll
    for (int mr = 0; mr < 4; ++mr) {
      #pragma unroll
      for (int v = 0; v < 4; ++v) {
        int m = m0 + mr * 16 + q * 4 + v;
        float z  = sigmf(accZ[mr][nr][v] + bz);
        float rr = sigmf(accR[mr][nr][v] + br);
        float cd = tanhf(accC[mr][nr][v] + bcv + rr * (accH[mr][nr][v] + bhcv));
        float h  = Hx[(size_t)m * 1024 + n];
        out[(size_t)m * 1024 + n] = (1.0f - z) * h + z * cd;
      }
    }
  }
}

// ---------------- last-resort fp32 fallback ----------------
__global__ __launch_bounds__(256) void gru_fallback(
    const float* __restrict__ In, const float* __restrict__ Hx,
    const float* __restrict__ Wih, const float* __restrict__ bih,
    const float* __restrict__ Whh, const float* __restrict__ bhh,
    const float* __restrict__ Wc, const float* __restrict__ bc,
    const float* __restrict__ Whc, const float* __restrict__ bhc,
    float* __restrict__ out)
{
  __shared__ float sIn[64][17], sHx[64][17];
  __shared__ float sW[6][16][68];
  const int tid = threadIdx.x;
  const int j = blockIdx.x & 15, i = blockIdx.x >> 4;
  const int tx = tid & 15, ty = tid >> 4;
  float accZ[4][4] = {}, accR[4][4] = {}, accC[4][4] = {}, accH[4][4] = {};
  const int ms = tid >> 2, kq = (tid & 3) * 4;
  const int wk = tid >> 4, wn4 = (tid & 15) * 4;
  for (int k0 = 0; k0 < 1024; k0 += 16) {
    __syncthreads();
    {
      float4 a = *(const float4*)&In[(size_t)(i * 64 + ms) * 1024 + k0 + kq];
      sIn[ms][kq] = a.x; sIn[ms][kq + 1] = a.y; sIn[ms][kq + 2] = a.z; sIn[ms][kq + 3] = a.w;
      float4 b = *(const float4*)&Hx[(size_t)(i * 64 + ms) * 1024 + k0 + kq];
      sHx[ms][kq] = b.x; sHx[ms][kq + 1] = b.y; sHx[ms][kq + 2] = b.z; sHx[ms][kq + 3] = b.w;
    }
    {
      float4 w0 = *(const float4*)&Wih[(size_t)(k0 + wk) * 2048 + j * 64 + wn4];
      float4 w1 = *(const float4*)&Wih[(size_t)(k0 + wk) * 2048 + 1024 + j * 64 + wn4];
      float4 w2 = *(const float4*)&Whh[(size_t)(k0 + wk) * 2048 + j * 64 + wn4];
      float4 w3 = *(const float4*)&Whh[(size_t)(k0 + wk) * 2048 + 1024 + j * 64 + wn4];
      float4 w4 = *(const float4*)&Wc[(size_t)(k0 + wk) * 1024 + j * 64 + wn4];
      float4 w5 = *(const float4*)&Whc[(size_t)(k0 + wk) * 1024 + j * 64 + wn4];
      sW[0][wk][wn4] = w0.x; sW[0][wk][wn4+1] = w0.y; sW[0][wk][wn4+2] = w0.z; sW[0][wk][wn4+3] = w0.w;
      sW[1][wk][wn4] = w1.x; sW[1][wk][wn4+1] = w1.y; sW[1][wk][wn4+2] = w1.z; sW[1][wk][wn4+3] = w1.w;
      sW[2][wk][wn4] = w2.x; sW[2][wk][wn4+1] = w2.y; sW[2][wk][wn4+2] = w2.z; sW[2][wk][wn4+3] = w2.w;
      sW[3][wk][wn4] = w3.x; sW[3][wk][wn4+1] = w3.y; sW[3][wk][wn4+2] = w3.z; sW[3][wk][wn4+3] = w3.w;
      sW[4][wk][wn4] = w4.x; sW[4][wk][wn4+1] = w4.y; sW[4][wk][wn4+2] = w4.z; sW[4][wk][wn4+3] = w4.w;
      sW[5][wk][wn4] = w5.x; sW[5][wk][wn4+1] = w5.y; sW[5][wk][wn4+2] = w5.z; sW[5][wk][wn4+3] = w5.w;
    }
    __syncthreads();
    for (int kk = 0; kk < 16; ++kk) {
      float aI[4], aH[4];
      #pragma unroll
      for (int im = 0; im < 4; ++im) { aI[im] = sIn[ty * 4 + im][kk]; aH[im] = sHx[ty * 4 + im][kk]; }
      #pragma unroll
      for (int jn = 0; jn < 4; ++jn) {
        float w0 = sW[0][kk][tx * 4 + jn], w1 = sW[1][kk][tx * 4 + jn], w2 = sW[2][kk][tx * 4 + jn];
        float w3 = sW[3][kk][tx * 4 + jn], w4 = sW[4][kk][tx * 4 + jn], w5 = sW[5][kk][tx * 4 + jn];
        #pragma unroll
        for (int im = 0; im < 4; ++im) {
          accZ[im][jn] += aI[im] * w0 + aH[im] * w2;
          accR[im][jn] += aI[im] * w1 + aH[im] * w3;
          accC[im][jn] += aI[im] * w4;
          accH[im][jn] += aH[im] * w5;
        }
      }
    }
  }
  #pragma unroll
  for (int jn = 0; jn < 4; ++jn) {
    int n = j * 64 + tx * 4 + jn;
    float bz  = bih[n] + bhh[n];
    float br  = bih[1024 + n] + bhh[1024 + n];
    float bcv = bc[n], bhcv = bhc[n];
    #pragma unroll
    for (int im = 0; im < 4; ++im) {
      int m = i * 64 + ty * 4 + im;
      float z  = sigmf(accZ[im][jn] + bz);
      float rr = sigmf(accR[im][jn] + br);
      float cd = tanhf(accC[im][jn] + bcv + rr * (accH[im][jn] + bhcv));
      float h  = Hx[(size_t)m * 1024 + n];
      out[(size_t)m * 1024 + n] = (1.0f - z) * h + z * cd;
    }
  }
}

extern "C" void kernel_launch(void* const* d_in, const int* in_sizes, int n_in,
                              void* d_out, int out_size, void* d_ws, size_t ws_size,
                              hipStream_t stream) {
  const float* In  = (const float*)d_in[0];
  const float* Hx  = (const float*)d_in[1];
  const float* Wih = (const float*)d_in[2];
  const float* bih = (const float*)d_in[3];
  const float* Whh = (const float*)d_in[4];
  const float* bhh = (const float*)d_in[5];
  const float* Wc  = (const float*)d_in[6];
  const float* bc  = (const float*)d_in[7];
  const float* Whc = (const float*)d_in[8];
  const float* bhc = (const float*)d_in[9];
  float* out = (float*)d_out;

  const size_t WS_NEED = 46137344ull;
  if (ws_size >= WS_NEED) {
    unsigned short* ws    = (unsigned short*)d_ws;
    unsigned short* wsIn  = ws;
    unsigned short* wsHx  = ws + 8388608;
    unsigned short* wsWih = ws + 16777216;
    unsigned short* wsWhh = ws + 18874368;
    unsigned short* wsWc  = ws + 20971520;
    unsigned short* wsWhc = ws + 22020096;
    cvt_all<<<11264, 256, 0, stream>>>(In, Hx, Wih, Whh, Wc, Whc,
                                       wsIn, wsHx, wsWih, wsWhh, wsWc, wsWhc);
    gru_gemm<<<1024, 256, 0, stream>>>(ws, Hx, bih, bhh, bc, bhc, out);
  } else {
    gru_fallback<<<2048, 256, 0, stream>>>(In, Hx, Wih, bih, Whh, bhh, Wc, bc, Whc, bhc, out);
  }
}